// Round 1
// baseline (3970.003 us; speedup 1.0000x reference)
//
#include <hip/hip_runtime.h>
#include <hip/hip_bf16.h>
#include <math.h>

// Problem constants
#define V_  32000
#define D_  512
#define NL_ 4
#define K_  32
#define B_  2
#define L_  1024
#define FF_ 2048
#define MR_ (B_ * L_)   // 2048 total rows

// ---------------------------------------------------------------------------
// Embedding gather: h[row,:] = embed[tokens[row],:]
// grid = MR_, block = 128 (float4 per thread covers D=512)
// ---------------------------------------------------------------------------
__global__ void gather_kernel(const int* __restrict__ tokens,
                              const float* __restrict__ embed,
                              float* __restrict__ h) {
    int row = blockIdx.x;
    int t = tokens[row];
    const float4* src = (const float4*)(embed + (size_t)t * D_);
    float4* dst = (float4*)(h + (size_t)row * D_);
    dst[threadIdx.x] = src[threadIdx.x];
}

// ---------------------------------------------------------------------------
// LayerNorm over D=512. grid = MR_, block = 256 (2 elems/thread).
// Safe in-place (values held in registers before write).
// ---------------------------------------------------------------------------
__global__ __launch_bounds__(256) void ln_kernel(const float* __restrict__ in,
                                                 const float* __restrict__ g,
                                                 const float* __restrict__ b,
                                                 float* __restrict__ out) {
    int row = blockIdx.x, tid = threadIdx.x;
    const float* rp = in + (size_t)row * D_;
    float v0 = rp[tid], v1 = rp[tid + 256];
    float s = v0 + v1, q = v0 * v0 + v1 * v1;
#pragma unroll
    for (int o = 32; o > 0; o >>= 1) {
        s += __shfl_down(s, o, 64);
        q += __shfl_down(q, o, 64);
    }
    __shared__ float ss[4], sq[4];
    if ((tid & 63) == 0) { ss[tid >> 6] = s; sq[tid >> 6] = q; }
    __syncthreads();
    float ts = ss[0] + ss[1] + ss[2] + ss[3];
    float tq = sq[0] + sq[1] + sq[2] + sq[3];
    float mean = ts * (1.0f / D_);
    float var = tq * (1.0f / D_) - mean * mean;
    float rstd = rsqrtf(var + 1e-5f);
    out[(size_t)row * D_ + tid]       = (v0 - mean) * rstd * g[tid] + b[tid];
    out[(size_t)row * D_ + tid + 256] = (v1 - mean) * rstd * g[tid + 256] + b[tid + 256];
}

// ---------------------------------------------------------------------------
// Generic fp32 GEMM: C[M,N] = epilogue(A[M,Kd] @ B + bias)
// flags: 1 = tanh, 2 = exact gelu, 4 = B is [N,Kd] row-major (transposed),
//        8 = multiply row m by inv_norm = rsqrt((m+1)*K_)
// res1/res2: optional residual adds (after activation).
// Requires M%64==0, N%64==0, Kd%16==0 (true for all shapes here).
// Block tile 64x64, K-tile 16, 256 threads, 4x4 microtile.
// ---------------------------------------------------------------------------
__global__ __launch_bounds__(256) void gemm_kernel(
    const float* __restrict__ A, const float* __restrict__ Bm,
    const float* __restrict__ bias, const float* __restrict__ res1,
    const float* __restrict__ res2, float* __restrict__ C,
    int M, int N, int Kd, int flags) {
    __shared__ float As[16][64];
    __shared__ float Bs[16][64];
    const int tid = threadIdx.x;
    const int m0 = blockIdx.y * 64, n0 = blockIdx.x * 64;
    const int tr = tid >> 4, tc = tid & 15;
    const int la_r = tid >> 2, la_k = (tid & 3) * 4;
    const int lb_k = tid >> 4, lb_n = (tid & 15) * 4;
    float acc[4][4] = {{0.f}};
    for (int k0 = 0; k0 < Kd; k0 += 16) {
        float4 av = *(const float4*)(A + (size_t)(m0 + la_r) * Kd + k0 + la_k);
        As[la_k + 0][la_r] = av.x; As[la_k + 1][la_r] = av.y;
        As[la_k + 2][la_r] = av.z; As[la_k + 3][la_r] = av.w;
        if (flags & 4) {
            float4 bv = *(const float4*)(Bm + (size_t)(n0 + la_r) * Kd + k0 + la_k);
            Bs[la_k + 0][la_r] = bv.x; Bs[la_k + 1][la_r] = bv.y;
            Bs[la_k + 2][la_r] = bv.z; Bs[la_k + 3][la_r] = bv.w;
        } else {
            float4 bv = *(const float4*)(Bm + (size_t)(k0 + lb_k) * N + n0 + lb_n);
            *(float4*)&Bs[lb_k][lb_n] = bv;
        }
        __syncthreads();
#pragma unroll
        for (int kk = 0; kk < 16; ++kk) {
            float4 a4 = *(const float4*)&As[kk][tr * 4];
            float4 b4 = *(const float4*)&Bs[kk][tc * 4];
            float aa[4] = {a4.x, a4.y, a4.z, a4.w};
            float bb[4] = {b4.x, b4.y, b4.z, b4.w};
#pragma unroll
            for (int i = 0; i < 4; ++i)
#pragma unroll
                for (int j = 0; j < 4; ++j)
                    acc[i][j] = fmaf(aa[i], bb[j], acc[i][j]);
        }
        __syncthreads();
    }
#pragma unroll
    for (int i = 0; i < 4; ++i) {
        const int m = m0 + tr * 4 + i;
        const float rs = (flags & 8) ? rsqrtf((float)(m + 1) * (float)K_) : 1.0f;
#pragma unroll
        for (int j = 0; j < 4; ++j) {
            const int n = n0 + tc * 4 + j;
            float vv = acc[i][j];
            if (bias) vv += bias[n];
            vv *= rs;
            if (flags & 1) vv = tanhf(vv);
            else if (flags & 2) vv = 0.5f * vv * (1.0f + erff(vv * 0.7071067811865476f));
            size_t idx = (size_t)m * N + n;
            if (res1) vv += res1[idx];
            if (res2) vv += res2[idx];
            C[idx] = vv;
        }
    }
}

// ---------------------------------------------------------------------------
// Phase kernel: per row (b*L + l):
//   z[k]  = t1[row,:] . cp_w2[:,k] + cp_b2[k]
//   cp    = tanh(z) * pi
//   tp    = pos_scale * l * freq[k] + content_scale * cp
//   c,s   = cos(tp), sin(tp)
// grid = MR_, block = 64 (2 threads per k-output, LDS reduce)
// ---------------------------------------------------------------------------
__global__ void phase_kernel(const float* __restrict__ t1,
                             const float* __restrict__ w2,
                             const float* __restrict__ b2,
                             const float* __restrict__ ps,
                             const float* __restrict__ cs,
                             int layer,
                             float* __restrict__ cbuf,
                             float* __restrict__ sbuf) {
    int row = blockIdx.x;
    int l = row & (L_ - 1);
    int tid = threadIdx.x;
    int k = tid & 31, hh = tid >> 5;
    const float* tr = t1 + (size_t)row * D_;
    float acc = 0.f;
    for (int d = hh * 256; d < hh * 256 + 256; ++d)
        acc = fmaf(tr[d], w2[d * K_ + k], acc);
    __shared__ float red[64];
    red[tid] = acc;
    __syncthreads();
    if (hh == 0) {
        float z = red[k] + red[k + 32] + b2[k];
        float cp = tanhf(z) * 3.14159265358979323846f;
        float freq = expf(-(float)k * (9.210340371976184f / (float)K_)); // 1/10000^(k/K)
        float tp = ps[layer] * (float)l * freq + cs[layer] * cp;
        cbuf[(size_t)row * K_ + k] = cosf(tp);
        sbuf[(size_t)row * K_ + k] = sinf(tp);
    }
}

// ---------------------------------------------------------------------------
// Score kernel: A[b][l][j] = (j<=l) ? sum_k c[l,k]c[j,k] + s[l,k]s[j,k] : 0
// grid = (L/16, L/16, B), block = (16,16)
// ---------------------------------------------------------------------------
__global__ __launch_bounds__(256) void score_kernel(const float* __restrict__ cbuf,
                                                    const float* __restrict__ sbuf,
                                                    float* __restrict__ Ab) {
    int b = blockIdx.z;
    int l0 = blockIdx.y * 16, j0 = blockIdx.x * 16;
    int tx = threadIdx.x, ty = threadIdx.y;
    int tid = ty * 16 + tx;
    __shared__ float Cl[16][32], Sl[16][32], Cj[16][32], Sj[16][32];
    const float* cb = cbuf + (size_t)b * L_ * K_;
    const float* sb = sbuf + (size_t)b * L_ * K_;
    for (int q = tid; q < 16 * 32; q += 256) {
        int rr = q >> 5, kk = q & 31;
        Cl[rr][kk] = cb[(size_t)(l0 + rr) * K_ + kk];
        Sl[rr][kk] = sb[(size_t)(l0 + rr) * K_ + kk];
        Cj[rr][kk] = cb[(size_t)(j0 + rr) * K_ + kk];
        Sj[rr][kk] = sb[(size_t)(j0 + rr) * K_ + kk];
    }
    __syncthreads();
    int l = l0 + ty, j = j0 + tx;
    float acc = 0.f;
#pragma unroll
    for (int kk = 0; kk < 32; ++kk)
        acc += Cl[ty][kk] * Cj[tx][kk] + Sl[ty][kk] * Sj[tx][kk];
    Ab[((size_t)b * L_ + l) * L_ + j] = (j <= l) ? acc : 0.f;
}

// ---------------------------------------------------------------------------
extern "C" void kernel_launch(void* const* d_in, const int* in_sizes, int n_in,
                              void* d_out, int out_size, void* d_ws, size_t ws_size,
                              hipStream_t stream) {
    const int*   tokens        = (const int*)d_in[0];
    const float* embed         = (const float*)d_in[1];
    const float* ln1_g         = (const float*)d_in[2];
    const float* ln1_b         = (const float*)d_in[3];
    const float* cp_w1         = (const float*)d_in[4];
    const float* cp_b1         = (const float*)d_in[5];
    const float* cp_w2         = (const float*)d_in[6];
    const float* cp_b2         = (const float*)d_in[7];
    const float* pos_scale     = (const float*)d_in[8];
    const float* content_scale = (const float*)d_in[9];
    const float* val_w         = (const float*)d_in[10];
    const float* val_b         = (const float*)d_in[11];
    const float* oln_g         = (const float*)d_in[12];
    const float* oln_b         = (const float*)d_in[13];
    const float* out_w         = (const float*)d_in[14];
    const float* out_b         = (const float*)d_in[15];
    const float* ln2_g         = (const float*)d_in[16];
    const float* ln2_b         = (const float*)d_in[17];
    const float* ffn_w1        = (const float*)d_in[18];
    const float* ffn_b1        = (const float*)d_in[19];
    const float* ffn_w2        = (const float*)d_in[20];
    const float* ffn_b2        = (const float*)d_in[21];
    const float* no_g          = (const float*)d_in[22];
    const float* no_b          = (const float*)d_in[23];
    const float* head_b        = (const float*)d_in[24];
    float* out = (float*)d_out;

    // Scratch layout: everything that is dead before the head GEMM lives in
    // d_out (65.5M floats; we use ~12.7M). Only hn (read while head GEMM
    // writes d_out) lives in d_ws (4 MB).
    float* Ab = out;                               // B*L*L   = 2,097,152
    float* ff = Ab + (size_t)B_ * L_ * L_;         // MR*FF   = 4,194,304
    float* h  = ff + (size_t)MR_ * FF_;            // MR*D
    float* x  = h  + (size_t)MR_ * D_;
    float* v  = x  + (size_t)MR_ * D_;
    float* r  = v  + (size_t)MR_ * D_;
    float* y  = r  + (size_t)MR_ * D_;
    float* t1 = y  + (size_t)MR_ * D_;
    float* cb = t1 + (size_t)MR_ * D_;             // MR*K
    float* sb = cb + (size_t)MR_ * K_;
    float* hn = (float*)d_ws;                      // MR*D floats = 4 MB

    gather_kernel<<<MR_, 128, 0, stream>>>(tokens, embed, h);

    for (int i = 0; i < NL_; ++i) {
        // x = LN(h)
        ln_kernel<<<MR_, 256, 0, stream>>>(h, ln1_g + i * D_, ln1_b + i * D_, x);
        // t1 = tanh(x @ cp_w1 + cp_b1)
        gemm_kernel<<<dim3(D_ / 64, MR_ / 64), 256, 0, stream>>>(
            x, cp_w1 + (size_t)i * D_ * D_, cp_b1 + i * D_,
            nullptr, nullptr, t1, MR_, D_, D_, 1);
        // c,s from t1 (small GEMM + tanh*pi + pos phase + cos/sin)
        phase_kernel<<<MR_, 64, 0, stream>>>(
            t1, cp_w2 + (size_t)i * D_ * K_, cp_b2 + i * K_,
            pos_scale, content_scale, i, cb, sb);
        // v = x @ val_w + val_b
        gemm_kernel<<<dim3(D_ / 64, MR_ / 64), 256, 0, stream>>>(
            x, val_w + (size_t)i * D_ * D_, val_b + i * D_,
            nullptr, nullptr, v, MR_, D_, D_, 0);
        // A = causal(C C^T + S S^T)
        score_kernel<<<dim3(L_ / 16, L_ / 16, B_), dim3(16, 16), 0, stream>>>(cb, sb, Ab);
        // r = (A @ v) * inv_norm   (per batch)
        for (int bb = 0; bb < B_; ++bb)
            gemm_kernel<<<dim3(D_ / 64, L_ / 64), 256, 0, stream>>>(
                Ab + (size_t)bb * L_ * L_, v + (size_t)bb * L_ * D_,
                nullptr, nullptr, nullptr, r + (size_t)bb * L_ * D_,
                L_, D_, L_, 8);
        // r = LN(r) in place
        ln_kernel<<<MR_, 256, 0, stream>>>(r, oln_g + i * D_, oln_b + i * D_, r);
        // h = h + x + (r @ out_w + out_b)
        gemm_kernel<<<dim3(D_ / 64, MR_ / 64), 256, 0, stream>>>(
            r, out_w + (size_t)i * D_ * D_, out_b + i * D_,
            h, x, h, MR_, D_, D_, 0);
        // y = LN(h)
        ln_kernel<<<MR_, 256, 0, stream>>>(h, ln2_g + i * D_, ln2_b + i * D_, y);
        // ff = gelu(y @ ffn_w1 + ffn_b1)
        gemm_kernel<<<dim3(FF_ / 64, MR_ / 64), 256, 0, stream>>>(
            y, ffn_w1 + (size_t)i * D_ * FF_, ffn_b1 + i * FF_,
            nullptr, nullptr, ff, MR_, FF_, D_, 2);
        // h = h + ff @ ffn_w2 + ffn_b2
        gemm_kernel<<<dim3(D_ / 64, MR_ / 64), 256, 0, stream>>>(
            ff, ffn_w2 + (size_t)i * FF_ * D_, ffn_b2 + i * D_,
            h, nullptr, h, MR_, D_, FF_, 0);
    }

    // hn = LN(h, no_g, no_b)
    ln_kernel<<<MR_, 256, 0, stream>>>(h, no_g, no_b, hn);
    // out = hn @ embed^T + head_b
    gemm_kernel<<<dim3(V_ / 64, MR_ / 64), 256, 0, stream>>>(
        hn, embed, head_b, nullptr, nullptr, out, MR_, V_, D_, 4);
}

// Round 2
// 1653.452 us; speedup vs baseline: 2.4010x; 2.4010x over previous
//
#include <hip/hip_runtime.h>
#include <hip/hip_bf16.h>
#include <math.h>

// Problem constants
#define V_  32000
#define D_  512
#define NL_ 4
#define K_  32
#define B_  2
#define L_  1024
#define FF_ 2048
#define MR_ (B_ * L_)   // 2048 total rows

typedef __bf16 bf16_t;
typedef __bf16 bf16x8 __attribute__((ext_vector_type(8)));
typedef float  f32x4  __attribute__((ext_vector_type(4)));

#define FLAG_TANH 1
#define FLAG_GELU 2
#define FLAG_INV  8

// async 16B global->LDS (wave-uniform LDS base + lane*16)
#define GLDS(gsrc, ldst) \
  __builtin_amdgcn_global_load_lds( \
      (const __attribute__((address_space(1))) unsigned int*)(const void*)(gsrc), \
      (__attribute__((address_space(3))) unsigned int*)(void*)(ldst), 16, 0, 0)

// ---------------------------------------------------------------------------
// Embedding gather
// ---------------------------------------------------------------------------
__global__ void gather_kernel(const int* __restrict__ tokens,
                              const float* __restrict__ embed,
                              float* __restrict__ h) {
    int row = blockIdx.x;
    int t = tokens[row];
    const float4* src = (const float4*)(embed + (size_t)t * D_);
    float4* dst = (float4*)(h + (size_t)row * D_);
    dst[threadIdx.x] = src[threadIdx.x];
}

// ---------------------------------------------------------------------------
// LayerNorm over D=512; optional fp32 and bf16 outputs.
// ---------------------------------------------------------------------------
__global__ __launch_bounds__(256) void ln_kernel(const float* __restrict__ in,
                                                 const float* __restrict__ g,
                                                 const float* __restrict__ b,
                                                 float* __restrict__ outf,
                                                 bf16_t* __restrict__ outb) {
    int row = blockIdx.x, tid = threadIdx.x;
    const float* rp = in + (size_t)row * D_;
    float v0 = rp[tid], v1 = rp[tid + 256];
    float s = v0 + v1, q = v0 * v0 + v1 * v1;
#pragma unroll
    for (int o = 32; o > 0; o >>= 1) {
        s += __shfl_down(s, o, 64);
        q += __shfl_down(q, o, 64);
    }
    __shared__ float ss[4], sq[4];
    if ((tid & 63) == 0) { ss[tid >> 6] = s; sq[tid >> 6] = q; }
    __syncthreads();
    float ts = ss[0] + ss[1] + ss[2] + ss[3];
    float tq = sq[0] + sq[1] + sq[2] + sq[3];
    float mean = ts * (1.0f / D_);
    float var = tq * (1.0f / D_) - mean * mean;
    float rstd = rsqrtf(var + 1e-5f);
    float o0 = (v0 - mean) * rstd * g[tid] + b[tid];
    float o1 = (v1 - mean) * rstd * g[tid + 256] + b[tid + 256];
    if (outf) {
        outf[(size_t)row * D_ + tid]       = o0;
        outf[(size_t)row * D_ + tid + 256] = o1;
    }
    if (outb) {
        outb[(size_t)row * D_ + tid]       = (bf16_t)o0;
        outb[(size_t)row * D_ + tid + 256] = (bf16_t)o1;
    }
}

// ---------------------------------------------------------------------------
// Transpose + fp32->bf16 convert: in fp32 [R][C] -> out bf16 [C][R]
// grid (C/32, R/32, Z), block 256
// ---------------------------------------------------------------------------
__global__ __launch_bounds__(256) void tconv_kernel(const float* __restrict__ in,
                                                    bf16_t* __restrict__ out,
                                                    int R, int C,
                                                    size_t inz, size_t outz) {
    __shared__ float t[32][33];
    const float* ip = in + (size_t)blockIdx.z * inz;
    bf16_t* op = out + (size_t)blockIdx.z * outz;
    int r0 = blockIdx.y * 32, c0 = blockIdx.x * 32;
    int tx = threadIdx.x & 31, ty = threadIdx.x >> 5;  // ty in [0,8)
#pragma unroll
    for (int rr = 0; rr < 4; ++rr)
        t[ty + rr * 8][tx] = ip[(size_t)(r0 + ty + rr * 8) * C + c0 + tx];
    __syncthreads();
#pragma unroll
    for (int rr = 0; rr < 4; ++rr)
        op[(size_t)(c0 + ty + rr * 8) * R + r0 + tx] = (bf16_t)t[tx][ty + rr * 8];
}

// ---------------------------------------------------------------------------
// MFMA bf16 GEMM: C[M,N] = epilogue(A[M,K] @ B^T[N,K])
//   A: bf16 [M][K] row-major (global_load_lds staged)
//   B: if !BF32: bf16 [N][K] row-major (global_load_lds staged)
//      if  BF32: fp32 [N][K] row-major (explicit convert staging) — head/embed
// flags: 1 tanh, 2 gelu, 8 inv_norm row scale.  res1/res2 fp32 residual adds.
// Outputs: Cf fp32 and/or Cb bf16 (nullable).
// Requires M%BM==0, N%BN==0, K%32==0.
// LDS chunk-XOR swizzle: source 16B-chunk q_src lives at lds chunk
// q_lds = q_src ^ ((row>>1)&3) — conflict-light reads, contiguous lane writes.
// ---------------------------------------------------------------------------
template<int BM, int BN, bool BF32>
__global__ __launch_bounds__(256) void mgemm(
    const bf16_t* __restrict__ A, const void* __restrict__ Bp,
    const float* __restrict__ bias, const float* __restrict__ res1,
    const float* __restrict__ res2, float* __restrict__ Cf,
    bf16_t* __restrict__ Cb, int M, int N, int Kd, int flags,
    long long strA, long long strB, long long strC) {
    __shared__ bf16_t sA[BM * 32];
    __shared__ bf16_t sB[BN * 32];
    const int tid = threadIdx.x;
    const int wave = tid >> 6, lane = tid & 63;
    const int lrow = lane & 15, quad = lane >> 4;
    const int m0 = blockIdx.y * BM, n0 = blockIdx.x * BN;
    const int z = blockIdx.z;
    A += (size_t)z * strA;
    const bf16_t* Bb = (const bf16_t*)Bp + (BF32 ? 0 : (size_t)z * strB);
    const float*  Bf = (const float*)Bp  + (BF32 ? (size_t)z * strB : 0);
    constexpr int TM = BM / 32, TN = BN / 32;  // 16x16 tiles per wave dim
    const int wm = (wave >> 1) * (BM / 2), wn = (wave & 1) * (BN / 2);
    f32x4 acc[TM][TN] = {};

    for (int k0 = 0; k0 < Kd; k0 += 32) {
        // --- stage A ---
#pragma unroll
        for (int rb = 0; rb < BM / 64; ++rb) {
            int rowblk = wave * (BM / 64) + rb;
            int ml = rowblk * 16 + (lane >> 2);
            int qs = (lane & 3) ^ ((ml >> 1) & 3);
            const bf16_t* src = A + (size_t)(m0 + ml) * Kd + k0 + qs * 8;
            GLDS(src, sA + rowblk * 512);
        }
        // --- stage B ---
        if (!BF32) {
#pragma unroll
            for (int rb = 0; rb < BN / 64; ++rb) {
                int rowblk = wave * (BN / 64) + rb;
                int nl = rowblk * 16 + (lane >> 2);
                int qs = (lane & 3) ^ ((nl >> 1) & 3);
                const bf16_t* src = Bb + (size_t)(n0 + nl) * Kd + k0 + qs * 8;
                GLDS(src, sB + rowblk * 512);
            }
        } else {
#pragma unroll
            for (int rb = 0; rb < (BN * 4) / 256; ++rb) {
                int s = rb * 256 + tid;
                int nl = s >> 2, ql = s & 3;
                int qs = ql ^ ((nl >> 1) & 3);
                const float* src = Bf + (size_t)(n0 + nl) * Kd + k0 + qs * 8;
                float4 f0 = ((const float4*)src)[0];
                float4 f1 = ((const float4*)src)[1];
                bf16x8 ov;
                ov[0] = (bf16_t)f0.x; ov[1] = (bf16_t)f0.y;
                ov[2] = (bf16_t)f0.z; ov[3] = (bf16_t)f0.w;
                ov[4] = (bf16_t)f1.x; ov[5] = (bf16_t)f1.y;
                ov[6] = (bf16_t)f1.z; ov[7] = (bf16_t)f1.w;
                *(bf16x8*)(sB + s * 8) = ov;
            }
        }
        __syncthreads();
        // --- fragments + MFMA ---
        bf16x8 af[TM], bv[TN];
#pragma unroll
        for (int i = 0; i < TM; ++i) {
            int row = wm + i * 16 + lrow;
            af[i] = *(const bf16x8*)(sA + (row * 4 + (quad ^ ((row >> 1) & 3))) * 8);
        }
#pragma unroll
        for (int j = 0; j < TN; ++j) {
            int rown = wn + j * 16 + lrow;
            bv[j] = *(const bf16x8*)(sB + (rown * 4 + (quad ^ ((rown >> 1) & 3))) * 8);
        }
#pragma unroll
        for (int i = 0; i < TM; ++i)
#pragma unroll
            for (int j = 0; j < TN; ++j)
                acc[i][j] = __builtin_amdgcn_mfma_f32_16x16x32_bf16(af[i], bv[j], acc[i][j], 0, 0, 0);
        __syncthreads();
    }

    // --- epilogue: C/D layout col=lane&15, row=quad*4+reg ---
    const size_t zo = (size_t)z * strC;
#pragma unroll
    for (int i = 0; i < TM; ++i) {
#pragma unroll
        for (int reg = 0; reg < 4; ++reg) {
            int m = m0 + wm + i * 16 + quad * 4 + reg;
            float rs = (flags & FLAG_INV) ? rsqrtf((float)(m - m0 + blockIdx.y * BM + 1) * (float)K_) : 1.0f;
#pragma unroll
            for (int j = 0; j < TN; ++j) {
                int n = n0 + wn + j * 16 + lrow;
                float vv = acc[i][j][reg];
                if (bias) vv += bias[n];
                vv *= rs;
                if (flags & FLAG_TANH) vv = tanhf(vv);
                else if (flags & FLAG_GELU) vv = 0.5f * vv * (1.0f + erff(vv * 0.7071067811865476f));
                size_t idx = zo + (size_t)m * N + n;
                if (res1) vv += res1[idx];
                if (res2) vv += res2[idx];
                if (Cf) Cf[idx] = vv;
                if (Cb) Cb[idx] = (bf16_t)vv;
            }
        }
    }
}

// ---------------------------------------------------------------------------
// Phase kernel (unchanged math): c,s = cos/sin(pos + content phases)
// ---------------------------------------------------------------------------
__global__ void phase_kernel(const float* __restrict__ t1,
                             const float* __restrict__ w2,
                             const float* __restrict__ b2,
                             const float* __restrict__ ps,
                             const float* __restrict__ cs,
                             int layer,
                             float* __restrict__ cbuf,
                             float* __restrict__ sbuf) {
    int row = blockIdx.x;
    int l = row & (L_ - 1);
    int tid = threadIdx.x;
    int k = tid & 31, hh = tid >> 5;
    const float* tr = t1 + (size_t)row * D_;
    float acc = 0.f;
    for (int d = hh * 256; d < hh * 256 + 256; ++d)
        acc = fmaf(tr[d], w2[d * K_ + k], acc);
    __shared__ float red[64];
    red[tid] = acc;
    __syncthreads();
    if (hh == 0) {
        float zz = red[k] + red[k + 32] + b2[k];
        float cp = tanhf(zz) * 3.14159265358979323846f;
        float freq = expf(-(float)k * (9.210340371976184f / (float)K_));
        float tp = ps[layer] * (float)l * freq + cs[layer] * cp;
        cbuf[(size_t)row * K_ + k] = cosf(tp);
        sbuf[(size_t)row * K_ + k] = sinf(tp);
    }
}

// ---------------------------------------------------------------------------
// Score kernel -> bf16: A[b][l][j] = (j<=l) ? sum_k c_l c_j + s_l s_j : 0
// ---------------------------------------------------------------------------
__global__ __launch_bounds__(256) void score_kernel(const float* __restrict__ cbuf,
                                                    const float* __restrict__ sbuf,
                                                    bf16_t* __restrict__ Ab) {
    int b = blockIdx.z;
    int l0 = blockIdx.y * 16, j0 = blockIdx.x * 16;
    int tx = threadIdx.x, ty = threadIdx.y;
    int tid = ty * 16 + tx;
    __shared__ float Cl[16][32], Sl[16][32], Cj[16][32], Sj[16][32];
    const float* cb = cbuf + (size_t)b * L_ * K_;
    const float* sb = sbuf + (size_t)b * L_ * K_;
    for (int q = tid; q < 16 * 32; q += 256) {
        int rr = q >> 5, kk = q & 31;
        Cl[rr][kk] = cb[(size_t)(l0 + rr) * K_ + kk];
        Sl[rr][kk] = sb[(size_t)(l0 + rr) * K_ + kk];
        Cj[rr][kk] = cb[(size_t)(j0 + rr) * K_ + kk];
        Sj[rr][kk] = sb[(size_t)(j0 + rr) * K_ + kk];
    }
    __syncthreads();
    int l = l0 + ty, j = j0 + tx;
    float acc = 0.f;
#pragma unroll
    for (int kk = 0; kk < 32; ++kk)
        acc += Cl[ty][kk] * Cj[tx][kk] + Sl[ty][kk] * Sj[tx][kk];
    Ab[((size_t)b * L_ + l) * L_ + j] = (bf16_t)((j <= l) ? acc : 0.f);
}

// ---------------------------------------------------------------------------
extern "C" void kernel_launch(void* const* d_in, const int* in_sizes, int n_in,
                              void* d_out, int out_size, void* d_ws, size_t ws_size,
                              hipStream_t stream) {
    const int*   tokens        = (const int*)d_in[0];
    const float* embed         = (const float*)d_in[1];
    const float* ln1_g         = (const float*)d_in[2];
    const float* ln1_b         = (const float*)d_in[3];
    const float* cp_w1         = (const float*)d_in[4];
    const float* cp_b1         = (const float*)d_in[5];
    const float* cp_w2         = (const float*)d_in[6];
    const float* cp_b2         = (const float*)d_in[7];
    const float* pos_scale     = (const float*)d_in[8];
    const float* content_scale = (const float*)d_in[9];
    const float* val_w         = (const float*)d_in[10];
    const float* val_b         = (const float*)d_in[11];
    const float* oln_g         = (const float*)d_in[12];
    const float* oln_b         = (const float*)d_in[13];
    const float* out_w         = (const float*)d_in[14];
    const float* out_b         = (const float*)d_in[15];
    const float* ln2_g         = (const float*)d_in[16];
    const float* ln2_b         = (const float*)d_in[17];
    const float* ffn_w1        = (const float*)d_in[18];
    const float* ffn_b1        = (const float*)d_in[19];
    const float* ffn_w2        = (const float*)d_in[20];
    const float* ffn_b2        = (const float*)d_in[21];
    const float* no_g          = (const float*)d_in[22];
    const float* no_b          = (const float*)d_in[23];
    const float* head_b        = (const float*)d_in[24];
    float* out = (float*)d_out;

    // Scratch in d_out (dead before head GEMM writes). Only hn_bf in d_ws.
    float* h  = out;                         // MR*D fp32 each
    float* x  = h  + (size_t)MR_ * D_;
    float* t1 = x  + (size_t)MR_ * D_;
    float* v  = t1 + (size_t)MR_ * D_;
    float* r  = v  + (size_t)MR_ * D_;
    float* cb = r  + (size_t)MR_ * D_;       // MR*K
    float* sb = cb + (size_t)MR_ * K_;
    bf16_t* x_bf  = (bf16_t*)(sb + (size_t)MR_ * K_);
    bf16_t* r_bf  = x_bf  + (size_t)MR_ * D_;
    bf16_t* y_bf  = r_bf  + (size_t)MR_ * D_;
    bf16_t* ff_bf = y_bf  + (size_t)MR_ * D_;          // MR*FF
    bf16_t* sc_bf = ff_bf + (size_t)MR_ * FF_;         // B*L*L
    bf16_t* vT_bf = sc_bf + (size_t)B_ * L_ * L_;      // B*D*L
    bf16_t* w1T   = vT_bf + (size_t)B_ * D_ * L_;      // NL*D*D
    bf16_t* vwT   = w1T   + (size_t)NL_ * D_ * D_;
    bf16_t* owT   = vwT   + (size_t)NL_ * D_ * D_;
    bf16_t* f1T   = owT   + (size_t)NL_ * D_ * D_;     // NL*FF*D
    bf16_t* f2T   = f1T   + (size_t)NL_ * FF_ * D_;    // NL*D*FF
    bf16_t* hn_bf = (bf16_t*)d_ws;                     // MR*D (2 MB)

    gather_kernel<<<MR_, 128, 0, stream>>>(tokens, embed, h);

    // Pre-transpose + convert all weights to bf16 [N][K]
    tconv_kernel<<<dim3(16, 16, NL_), 256, 0, stream>>>(cp_w1, w1T, D_, D_, (size_t)D_ * D_, (size_t)D_ * D_);
    tconv_kernel<<<dim3(16, 16, NL_), 256, 0, stream>>>(val_w, vwT, D_, D_, (size_t)D_ * D_, (size_t)D_ * D_);
    tconv_kernel<<<dim3(16, 16, NL_), 256, 0, stream>>>(out_w, owT, D_, D_, (size_t)D_ * D_, (size_t)D_ * D_);
    tconv_kernel<<<dim3(64, 16, NL_), 256, 0, stream>>>(ffn_w1, f1T, D_, FF_, (size_t)D_ * FF_, (size_t)D_ * FF_);
    tconv_kernel<<<dim3(16, 64, NL_), 256, 0, stream>>>(ffn_w2, f2T, FF_, D_, (size_t)FF_ * D_, (size_t)FF_ * D_);

    for (int i = 0; i < NL_; ++i) {
        // x = LN(h) (fp32 + bf16)
        ln_kernel<<<MR_, 256, 0, stream>>>(h, ln1_g + i * D_, ln1_b + i * D_, x, x_bf);
        // t1 = tanh(x @ cp_w1 + cp_b1)  fp32
        mgemm<64, 64, false><<<dim3(8, 32, 1), 256, 0, stream>>>(
            x_bf, w1T + (size_t)i * D_ * D_, cp_b1 + i * D_,
            nullptr, nullptr, t1, nullptr, MR_, D_, D_, FLAG_TANH, 0, 0, 0);
        // c,s phases
        phase_kernel<<<MR_, 64, 0, stream>>>(
            t1, cp_w2 + (size_t)i * D_ * K_, cp_b2 + i * K_,
            pos_scale, content_scale, i, cb, sb);
        // v = x @ val_w + val_b  fp32
        mgemm<64, 64, false><<<dim3(8, 32, 1), 256, 0, stream>>>(
            x_bf, vwT + (size_t)i * D_ * D_, val_b + i * D_,
            nullptr, nullptr, v, nullptr, MR_, D_, D_, 0, 0, 0, 0);
        // vT (bf16, [b][D][L]) for the A@v GEMM B-operand
        tconv_kernel<<<dim3(16, 32, B_), 256, 0, stream>>>(
            v, vT_bf, L_, D_, (size_t)L_ * D_, (size_t)D_ * L_);
        // scores (bf16, causal)
        score_kernel<<<dim3(L_ / 16, L_ / 16, B_), dim3(16, 16), 0, stream>>>(cb, sb, sc_bf);
        // r = (A @ v) * inv_norm  (batched over z)
        mgemm<64, 64, false><<<dim3(8, 16, B_), 256, 0, stream>>>(
            sc_bf, vT_bf, nullptr, nullptr, nullptr, r, nullptr,
            L_, D_, L_, FLAG_INV, (long long)L_ * L_, (long long)D_ * L_, (long long)L_ * D_);
        // r_bf = LN(r)
        ln_kernel<<<MR_, 256, 0, stream>>>(r, oln_g + i * D_, oln_b + i * D_, nullptr, r_bf);
        // h = h + x + (r_bf @ out_w + out_b)
        mgemm<64, 64, false><<<dim3(8, 32, 1), 256, 0, stream>>>(
            r_bf, owT + (size_t)i * D_ * D_, out_b + i * D_,
            h, x, h, nullptr, MR_, D_, D_, 0, 0, 0, 0);
        // y_bf = LN(h)
        ln_kernel<<<MR_, 256, 0, stream>>>(h, ln2_g + i * D_, ln2_b + i * D_, nullptr, y_bf);
        // ff_bf = gelu(y @ ffn_w1 + b1)  (bf16 only)
        mgemm<128, 128, false><<<dim3(16, 16, 1), 256, 0, stream>>>(
            y_bf, f1T + (size_t)i * FF_ * D_, ffn_b1 + i * FF_,
            nullptr, nullptr, nullptr, ff_bf, MR_, FF_, D_, FLAG_GELU, 0, 0, 0);
        // h = h + ff @ ffn_w2 + b2
        mgemm<64, 64, false><<<dim3(8, 32, 1), 256, 0, stream>>>(
            ff_bf, f2T + (size_t)i * D_ * FF_, ffn_b2 + i * D_,
            h, nullptr, h, nullptr, MR_, D_, FF_, 0, 0, 0, 0);
    }

    // hn_bf = LN(h)
    ln_kernel<<<MR_, 256, 0, stream>>>(h, no_g, no_b, nullptr, hn_bf);
    // out = hn @ embed^T + head_b   (embed fp32 converted in staging)
    mgemm<128, 128, true><<<dim3(V_ / 128, MR_ / 128, 1), 256, 0, stream>>>(
        hn_bf, embed, head_b, nullptr, nullptr, out, nullptr,
        MR_, V_, D_, 0, 0, 0, 0);
}